// Round 7
// baseline (208.729 us; speedup 1.0000x reference)
//
#include <hip/hip_runtime.h>
#include <hip/hip_bf16.h>

#define B_ 4
#define L_ 8192
#define D_ 256
#define J_ 13

typedef __attribute__((ext_vector_type(4))) float f32x4;
typedef __attribute__((ext_vector_type(8))) short bf16x8;
typedef __attribute__((ext_vector_type(8))) unsigned short u16x8;

__device__ __forceinline__ void async_copy16(const void* g, void* l) {
    __builtin_amdgcn_global_load_lds(
        (const __attribute__((address_space(1))) void*)g,
        (__attribute__((address_space(3))) void*)l, 16, 0, 0);
}

// pack two f32 -> bf16 pair (round-half-up; inputs finite)
__device__ __forceinline__ unsigned int packbf(float a, float b) {
    unsigned int ua = __float_as_uint(a) + 0x8000u;
    unsigned int ub = __float_as_uint(b) + 0x8000u;
    return (ua >> 16) | (ub & 0xFFFF0000u);
}
__device__ __forceinline__ unsigned short packbf1(float a) {
    return (unsigned short)((__float_as_uint(a) + 0x8000u) >> 16);
}

// ---------------- K1: fused wt-transpose (blocks 0..31) + RMSNorm/transpose ------
// wt: conv_w (256,512) f32 -> Wt (512,256) bf16
// rms: x (B,L,D) f32 -> xtb (B,D,L) bf16
__global__ void rms_wt_kernel(const float* __restrict__ x, const float* __restrict__ scale,
                              ushort* __restrict__ xtb,
                              const float* __restrict__ W, ushort* __restrict__ Wt) {
    __shared__ __align__(16) float sm[32 * 257 + 32];
    int blk = blockIdx.x;
    int tid = threadIdx.x;
    if (blk < 32) {
        float (*tile)[65] = (float(*)[65])sm;
        int dt = blk >> 3, et = blk & 7;
        int d0 = dt * 64, e0 = et * 64;
#pragma unroll
        for (int k = 0; k < 16; ++k) {
            int i = tid + k * 256;
            int r = i >> 6, c = i & 63;
            tile[r][c] = W[(d0 + r) * 512 + e0 + c];
        }
        __syncthreads();
#pragma unroll
        for (int k = 0; k < 16; ++k) {
            int i = tid + k * 256;
            int r = i >> 6, c = i & 63;
            Wt[(e0 + r) * 256 + d0 + c] = packbf1(tile[c][r]);
        }
        return;
    }
    blk -= 32;                        // b*256 + ltile
    float (*tile)[257] = (float(*)[257])sm;
    float* invl = sm + 32 * 257;
    int b  = blk >> 8;
    int l0 = (blk & 255) << 5;
    const float* src = x + ((size_t)(b * L_ + l0)) * D_;
#pragma unroll
    for (int k = 0; k < 32; ++k) tile[k][tid] = src[k * D_ + tid];
    __syncthreads();
    int wave = tid >> 6, lane = tid & 63;
#pragma unroll
    for (int rr = 0; rr < 8; ++rr) {
        int r = wave * 8 + rr;
        float s = 0.f;
#pragma unroll
        for (int q = 0; q < 4; ++q) { float v = tile[r][lane + 64 * q]; s += v * v; }
#pragma unroll
        for (int off = 32; off; off >>= 1) s += __shfl_xor(s, off);
        if (lane == 0) invl[r] = rsqrtf(s * (1.0f / 256.0f) + 1e-6f);
    }
    __syncthreads();
    uint* dst32 = (uint*)xtb;
#pragma unroll
    for (int k = 0; k < 16; ++k) {
        int i = tid + k * 256;         // 4096 (d, l-pair) slots
        int d = i >> 4, lp = (i & 15) * 2;
        float v0 = tile[lp][d]     * invl[lp]     * scale[d];
        float v1 = tile[lp + 1][d] * invl[lp + 1] * scale[d];
        dst32[(((size_t)(b * D_ + d)) * L_ + l0 + lp) >> 1] = packbf(v0, v1);
    }
}

// ---------------- K2: 13-level dilated depthwise cascade + gelu ------------------
// 2 channels/block, 512 threads (256/channel), 32 f32 elems/thread in registers.
// Levels dil=1..16 in-register (top-16 boundary via LDS); dil=32..4096 full-chunk
// exchange with thread ct-dil/32. All LDS exchange in bf16, slot stride 80B
// (20-bank lane stride -> conflict-free b128). R6 lesson: kernel was
// barrier/latency-chain bound (all pipes <35%), so: fewer, fatter chains.
#define LEVEL_SMALL(d, jj)                                                       \
    do {                                                                         \
        uint4 pk;                                                                \
        pk.x = packbf(cc[16], cc[17]); pk.y = packbf(cc[18], cc[19]);            \
        pk.z = packbf(cc[20], cc[21]); pk.w = packbf(cc[22], cc[23]);            \
        *(uint4*)(ex + slot + 16) = pk;                                          \
        pk.x = packbf(cc[24], cc[25]); pk.y = packbf(cc[26], cc[27]);            \
        pk.z = packbf(cc[28], cc[29]); pk.w = packbf(cc[30], cc[31]);            \
        *(uint4*)(ex + slot + 24) = pk;                                          \
        __syncthreads();                                                         \
        float pt[16];                                                            \
        if (ct > 0) {                                                            \
            uint4 a  = *(const uint4*)(ex + slot - 40 + 16);                     \
            uint4 bq = *(const uint4*)(ex + slot - 40 + 24);                     \
            uint uu[8] = {a.x, a.y, a.z, a.w, bq.x, bq.y, bq.z, bq.w};           \
            _Pragma("unroll") for (int q = 0; q < 8; ++q) {                      \
                pt[2*q]   = __uint_as_float(uu[q] << 16);                        \
                pt[2*q+1] = __uint_as_float(uu[q] & 0xFFFF0000u); }              \
        } else { _Pragma("unroll") for (int q = 0; q < 16; ++q) pt[q] = 0.f; }   \
        __syncthreads();                                                         \
        float wj = w[((jj) + 1) * D_ + c];                                       \
        _Pragma("unroll")                                                        \
        for (int i = 31; i >= 0; --i) {                                          \
            float pv = (i >= (d)) ? cc[i - (d)] : pt[16 + i - (d)];              \
            float nv = h00 * pv + h01 * cc[i];                                   \
            y[i] += wj * (h10 * pv + h11 * cc[i]);                               \
            cc[i] = nv;                                                          \
        }                                                                        \
    } while (0)

__global__ void __launch_bounds__(512, 4) cascade_kernel(
    const ushort* __restrict__ xt, const float* __restrict__ h0,
    const float* __restrict__ h1, const float* __restrict__ w,
    ushort* __restrict__ ygt) {
    __shared__ __align__(16) ushort ex[512 * 40];   // 40 KB
    int blk = blockIdx.x;                  // b*128 + cpair
    int b = blk >> 7;
    int t = threadIdx.x;
    int ch = t >> 8;
    int ct = t & 255;
    int c = ((blk & 127) << 1) + ch;
    int slot = t * 40;                     // ushort offset, 80B stride
    float h00 = h0[2*c], h01 = h0[2*c+1];
    float h10 = h1[2*c], h11 = h1[2*c+1];
    float w0 = w[c], wlast = w[14 * D_ + c];

    const ushort* src = xt + ((size_t)(b * D_ + c)) * L_ + ct * 32;
    float cc[32], y[32];
#pragma unroll
    for (int m = 0; m < 4; ++m) {
        u16x8 v = *(const u16x8*)(src + m * 8);
#pragma unroll
        for (int i = 0; i < 8; ++i) cc[m*8+i] = __uint_as_float(((uint)v[i]) << 16);
    }
#pragma unroll
    for (int i = 0; i < 32; ++i) y[i] = w0 * cc[i];

    LEVEL_SMALL(1, 0);
    LEVEL_SMALL(2, 1);
    LEVEL_SMALL(4, 2);
    LEVEL_SMALL(8, 3);
    LEVEL_SMALL(16, 4);

#pragma unroll 1
    for (int j = 5; j < J_; ++j) {
        int dT = 1 << (j - 5);
        float wj = w[(j + 1) * D_ + c];
#pragma unroll
        for (int m = 0; m < 4; ++m) {
            uint4 pk;
            pk.x = packbf(cc[8*m],   cc[8*m+1]); pk.y = packbf(cc[8*m+2], cc[8*m+3]);
            pk.z = packbf(cc[8*m+4], cc[8*m+5]); pk.w = packbf(cc[8*m+6], cc[8*m+7]);
            *(uint4*)(ex + slot + 8 * m) = pk;
        }
        __syncthreads();
        bool has = (ct >= dT);
        int pbase = slot - dT * 40;
#pragma unroll
        for (int h = 0; h < 2; ++h) {
            float pv[16];
            if (has) {
                uint4 a  = *(const uint4*)(ex + pbase + 16 * h);
                uint4 bq = *(const uint4*)(ex + pbase + 16 * h + 8);
                uint uu[8] = {a.x, a.y, a.z, a.w, bq.x, bq.y, bq.z, bq.w};
#pragma unroll
                for (int q = 0; q < 8; ++q) {
                    pv[2*q]   = __uint_as_float(uu[q] << 16);
                    pv[2*q+1] = __uint_as_float(uu[q] & 0xFFFF0000u);
                }
            } else {
#pragma unroll
                for (int q = 0; q < 16; ++q) pv[q] = 0.f;
            }
#pragma unroll
            for (int i = 0; i < 16; ++i) {
                int e = 16 * h + i;
                float nv = h00 * pv[i] + h01 * cc[e];
                y[e] += wj * (h10 * pv[i] + h11 * cc[e]);
                cc[e] = nv;
            }
        }
        __syncthreads();
    }
    // ---- epilogue: + wlast*a, gelu(tanh approx), bf16 store (64B/thread) ----
    ushort* dst = ygt + ((size_t)(b * D_ + c)) * L_ + ct * 32;
#pragma unroll
    for (int m = 0; m < 4; ++m) {
        float g[8];
#pragma unroll
        for (int q = 0; q < 8; ++q) {
            float v = y[8*m+q] + wlast * cc[8*m+q];
            float u = 0.7978845608028654f * (v + 0.044715f * v * v * v);
            g[q] = 0.5f * v * (1.f + tanhf(u));
        }
        uint4 pk;
        pk.x = packbf(g[0], g[1]); pk.y = packbf(g[2], g[3]);
        pk.z = packbf(g[4], g[5]); pk.w = packbf(g[6], g[7]);
        *(uint4*)(dst + 8 * m) = pk;
    }
}

// ---------------- K2.5: transpose ygt (B,D,L) bf16 -> yg (B,L,D) bf16 ------------
__global__ void trans_kernel(const ushort* __restrict__ ygt, ushort* __restrict__ yg) {
    __shared__ uint tile[64][33];
    int blk = blockIdx.x;            // b*512 + dt*128 + lt
    int b = blk >> 9;
    int rem = blk & 511;
    int dt = rem >> 7, lt = rem & 127;
    int d0 = dt * 64, l0 = lt * 64;
    int tid = threadIdx.x;
    const uint* src = (const uint*)ygt;
#pragma unroll
    for (int k = 0; k < 8; ++k) {
        int i = tid + k * 256;
        int r = i >> 5, cp = i & 31;
        tile[r][cp] = src[(((size_t)(b * D_ + d0 + r)) * L_ + l0) / 2 + cp];
    }
    __syncthreads();
    const ushort* ts = (const ushort*)tile;   // viewed as [64][66]
#pragma unroll
    for (int k = 0; k < 16; ++k) {
        int i = tid + k * 256;
        int r2 = i >> 6, c2 = i & 63;
        yg[((size_t)(b * L_ + l0 + r2)) * D_ + d0 + c2] = ts[c2 * 66 + r2];
    }
}

// ---------------- K3: bf16 MFMA GEMM + bias + GLU + residual ---------------------
__global__ void __launch_bounds__(256) gemm_kernel(
    const ushort* __restrict__ yg, const ushort* __restrict__ Wt,
    const float* __restrict__ cb, const float* __restrict__ x,
    float* __restrict__ out) {
    __shared__ __align__(16) char smem[32768];
    ushort* As = (ushort*)smem;            // [128 rows][8 granules of 8 bf16]
    ushort* Bs = As + 128 * 64;            // same shape
    int blk = blockIdx.x;            // b*256 + ltile*4 + etile
    int b = blk >> 8;
    int rem = blk & 255;
    int ltile = rem >> 2, et = rem & 3;
    int l0 = ltile * 128, e0 = et * 64;
    int tid = threadIdx.x;
    int wave = tid >> 6, lane = tid & 63;
    int wm = wave >> 1, wn = wave & 1;
    int m0 = wm * 64;

    int srow_in = (lane >> 3);             // 0..7 within volley
    int sg = lane & 7;                     // swizzled granule g'
    int sgg = sg ^ srow_in;                // unswizzled granule g
    f32x4 acc[4][4];
#pragma unroll
    for (int i = 0; i < 4; ++i)
#pragma unroll
        for (int j = 0; j < 4; ++j) acc[i][j] = (f32x4)0.f;

    for (int kc = 0; kc < 4; ++kc) {
        __syncthreads();
#pragma unroll
        for (int v = 0; v < 4; ++v) {
            int r = wave * 32 + v * 8 + srow_in;
            async_copy16(yg + ((size_t)(b * L_ + l0 + r)) * D_ + kc * 64 + sgg * 8,
                         As + r * 64 + sg * 8);
            int e = (r < 64) ? (e0 + r) : (256 + e0 + (r - 64));
            async_copy16(Wt + e * 256 + kc * 64 + sgg * 8,
                         Bs + r * 64 + sg * 8);
        }
        __syncthreads();
#pragma unroll
        for (int kk = 0; kk < 2; ++kk) {
            bf16x8 af[4], bfr[4];
            int g = kk * 4 + (lane >> 4);
            int gp = (g ^ (lane & 7)) * 8;
#pragma unroll
            for (int mt = 0; mt < 4; ++mt)
                af[mt] = *(const bf16x8*)(As + (m0 + mt * 16 + (lane & 15)) * 64 + gp);
#pragma unroll
            for (int nt = 0; nt < 4; ++nt) {
                int n = wn * 32 + (nt & 1) * 16 + (nt >> 1) * 64 + (lane & 15);
                bfr[nt] = *(const bf16x8*)(Bs + n * 64 + gp);
            }
#pragma unroll
            for (int mt = 0; mt < 4; ++mt)
#pragma unroll
                for (int nt = 0; nt < 4; ++nt)
                    acc[mt][nt] = __builtin_amdgcn_mfma_f32_16x16x32_bf16(
                        af[mt], bfr[nt], acc[mt][nt], 0, 0, 0);
        }
    }
    __syncthreads();
    float* epi = (float*)smem;
    int row_in = (lane >> 4) * 4;
    int col = lane & 15;
#pragma unroll
    for (int mt = 0; mt < 4; ++mt) {
#pragma unroll
        for (int p = 0; p < 2; ++p) {
            f32x4 uacc = acc[mt][p];
            f32x4 vacc = acc[mt][p + 2];
            int ee = wn * 32 + p * 16 + col;
            float bu = cb[e0 + ee], bv = cb[256 + e0 + ee];
#pragma unroll
            for (int r = 0; r < 4; ++r) {
                int ll = m0 + mt * 16 + row_in + r;
                float u = uacc[r] + bu;
                float v = vacc[r] + bv;
                float g = u / (1.f + __expf(-v));
                epi[ll * 64 + (ee ^ ((ll & 4) ? 16 : 0))] = g;
            }
        }
    }
    __syncthreads();
#pragma unroll
    for (int k = 0; k < 8; ++k) {
        int i = tid + k * 256;
        int ll = i >> 4, e4 = i & 15;
        int exo = (e4 * 4) ^ ((ll & 4) ? 16 : 0);
        float4 gv = *(const float4*)(epi + ll * 64 + exo);
        size_t gidx = ((size_t)(b * L_ + l0 + ll)) * D_ + e0 + e4 * 4;
        float4 xv = *(const float4*)(x + gidx);
        float4 ov;
        ov.x = gv.x + xv.x; ov.y = gv.y + xv.y;
        ov.z = gv.z + xv.z; ov.w = gv.w + xv.w;
        *(float4*)(out + gidx) = ov;
    }
}

extern "C" void kernel_launch(void* const* d_in, const int* in_sizes, int n_in,
                              void* d_out, int out_size, void* d_ws, size_t ws_size,
                              hipStream_t stream) {
    const float* x  = (const float*)d_in[0];
    const float* rs = (const float*)d_in[1];
    const float* h0 = (const float*)d_in[2];
    const float* h1 = (const float*)d_in[3];
    const float* w  = (const float*)d_in[4];
    const float* cw = (const float*)d_in[5];
    const float* cb = (const float*)d_in[6];
    float* out = (float*)d_out;
    char* ws = (char*)d_ws;

    ushort* xtb = (ushort*)ws;                       // 16,777,216 B (bf16)
    ushort* ygt = (ushort*)(ws + 16777216);          // 16,777,216 B (bf16)
    ushort* Wt  = (ushort*)(ws + 33554432);          //    262,144 B (bf16)
    ushort* yg  = (ushort*)ws;                       // alias xtb (dead after cascade)

    rms_wt_kernel<<<1056, 256, 0, stream>>>(x, rs, xtb, cw, Wt);
    cascade_kernel<<<512, 512, 0, stream>>>(xtb, h0, h1, w, ygt);
    trans_kernel<<<2048, 256, 0, stream>>>(ygt, yg);
    gemm_kernel<<<1024, 256, 0, stream>>>(yg, Wt, cb, x, out);
}

// Round 8
// 208.062 us; speedup vs baseline: 1.0032x; 1.0032x over previous
//
#include <hip/hip_runtime.h>
#include <hip/hip_bf16.h>

#define B_ 4
#define L_ 8192
#define D_ 256
#define J_ 13

typedef __attribute__((ext_vector_type(4))) float f32x4;
typedef __attribute__((ext_vector_type(8))) short bf16x8;
typedef __attribute__((ext_vector_type(8))) unsigned short u16x8;

__device__ __forceinline__ void async_copy16(const void* g, void* l) {
    __builtin_amdgcn_global_load_lds(
        (const __attribute__((address_space(1))) void*)g,
        (__attribute__((address_space(3))) void*)l, 16, 0, 0);
}

// pack two f32 -> bf16 pair (round-half-up; inputs finite)
__device__ __forceinline__ unsigned int packbf(float a, float b) {
    unsigned int ua = __float_as_uint(a) + 0x8000u;
    unsigned int ub = __float_as_uint(b) + 0x8000u;
    return (ua >> 16) | (ub & 0xFFFF0000u);
}
__device__ __forceinline__ unsigned short packbf1(float a) {
    return (unsigned short)((__float_as_uint(a) + 0x8000u) >> 16);
}

// ---------------- K1: fused wt-transpose (blocks 0..31) + RMSNorm/transpose ------
// wt: conv_w (256,512) f32 -> Wt (512,256) bf16
// rms: x (B,L,D) f32 -> xtb (B,D,L) bf16
__global__ void rms_wt_kernel(const float* __restrict__ x, const float* __restrict__ scale,
                              ushort* __restrict__ xtb,
                              const float* __restrict__ W, ushort* __restrict__ Wt) {
    __shared__ __align__(16) float sm[32 * 257 + 32];
    int blk = blockIdx.x;
    int tid = threadIdx.x;
    if (blk < 32) {
        float (*tile)[65] = (float(*)[65])sm;
        int dt = blk >> 3, et = blk & 7;
        int d0 = dt * 64, e0 = et * 64;
#pragma unroll
        for (int k = 0; k < 16; ++k) {
            int i = tid + k * 256;
            int r = i >> 6, c = i & 63;
            tile[r][c] = W[(d0 + r) * 512 + e0 + c];
        }
        __syncthreads();
#pragma unroll
        for (int k = 0; k < 16; ++k) {
            int i = tid + k * 256;
            int r = i >> 6, c = i & 63;
            Wt[(e0 + r) * 256 + d0 + c] = packbf1(tile[c][r]);
        }
        return;
    }
    blk -= 32;                        // b*256 + ltile
    float (*tile)[257] = (float(*)[257])sm;
    float* invl = sm + 32 * 257;
    int b  = blk >> 8;
    int l0 = (blk & 255) << 5;
    const float* src = x + ((size_t)(b * L_ + l0)) * D_;
#pragma unroll
    for (int k = 0; k < 32; ++k) tile[k][tid] = src[k * D_ + tid];
    __syncthreads();
    int wave = tid >> 6, lane = tid & 63;
#pragma unroll
    for (int rr = 0; rr < 8; ++rr) {
        int r = wave * 8 + rr;
        float s = 0.f;
#pragma unroll
        for (int q = 0; q < 4; ++q) { float v = tile[r][lane + 64 * q]; s += v * v; }
#pragma unroll
        for (int off = 32; off; off >>= 1) s += __shfl_xor(s, off);
        if (lane == 0) invl[r] = rsqrtf(s * (1.0f / 256.0f) + 1e-6f);
    }
    __syncthreads();
    uint* dst32 = (uint*)xtb;
#pragma unroll
    for (int k = 0; k < 16; ++k) {
        int i = tid + k * 256;         // 4096 (d, l-pair) slots
        int d = i >> 4, lp = (i & 15) * 2;
        float v0 = tile[lp][d]     * invl[lp]     * scale[d];
        float v1 = tile[lp + 1][d] * invl[lp + 1] * scale[d];
        dst32[(((size_t)(b * D_ + d)) * L_ + l0 + lp) >> 1] = packbf(v0, v1);
    }
}

// ---------------- K2: 13-level dilated depthwise cascade + gelu ------------------
// 2 channels/block, 512 threads (256/channel), 32 f32 elems/thread in registers.
// Levels dil=1..16 in-register (top-16 boundary via LDS); dil=32..4096 full-chunk
// exchange with thread ct-dil/32. All LDS exchange in bf16, slot stride 80B.
// R7 lesson: __launch_bounds__(512,4)'s 2nd arg is a MINIMUM waves/EU — the
// compiler targeted 8 waves/EU (64-VGPR budget) against ~104 live regs and
// spilled 40 regs/thread to scratch (FETCH 90MB, WRITE 160MB). Pin exactly
// 4 waves/EU via amdgpu_waves_per_eu(4,4) -> 128-VGPR budget, no spill.
#define LEVEL_SMALL(d, jj)                                                       \
    do {                                                                         \
        uint4 pk;                                                                \
        pk.x = packbf(cc[16], cc[17]); pk.y = packbf(cc[18], cc[19]);            \
        pk.z = packbf(cc[20], cc[21]); pk.w = packbf(cc[22], cc[23]);            \
        *(uint4*)(ex + slot + 16) = pk;                                          \
        pk.x = packbf(cc[24], cc[25]); pk.y = packbf(cc[26], cc[27]);            \
        pk.z = packbf(cc[28], cc[29]); pk.w = packbf(cc[30], cc[31]);            \
        *(uint4*)(ex + slot + 24) = pk;                                          \
        __syncthreads();                                                         \
        float pt[16];                                                            \
        if (ct > 0) {                                                            \
            uint4 a  = *(const uint4*)(ex + slot - 40 + 16);                     \
            uint4 bq = *(const uint4*)(ex + slot - 40 + 24);                     \
            uint uu[8] = {a.x, a.y, a.z, a.w, bq.x, bq.y, bq.z, bq.w};           \
            _Pragma("unroll") for (int q = 0; q < 8; ++q) {                      \
                pt[2*q]   = __uint_as_float(uu[q] << 16);                        \
                pt[2*q+1] = __uint_as_float(uu[q] & 0xFFFF0000u); }              \
        } else { _Pragma("unroll") for (int q = 0; q < 16; ++q) pt[q] = 0.f; }   \
        __syncthreads();                                                         \
        float wj = w[((jj) + 1) * D_ + c];                                       \
        _Pragma("unroll")                                                        \
        for (int i = 31; i >= 0; --i) {                                          \
            float pv = (i >= (d)) ? cc[i - (d)] : pt[16 + i - (d)];              \
            float nv = h00 * pv + h01 * cc[i];                                   \
            y[i] += wj * (h10 * pv + h11 * cc[i]);                               \
            cc[i] = nv;                                                          \
        }                                                                        \
    } while (0)

__global__ void __launch_bounds__(512)
__attribute__((amdgpu_waves_per_eu(4, 4))) cascade_kernel(
    const ushort* __restrict__ xt, const float* __restrict__ h0,
    const float* __restrict__ h1, const float* __restrict__ w,
    ushort* __restrict__ ygt) {
    __shared__ __align__(16) ushort ex[512 * 40];   // 40 KB
    int blk = blockIdx.x;                  // b*128 + cpair
    int b = blk >> 7;
    int t = threadIdx.x;
    int ch = t >> 8;
    int ct = t & 255;
    int c = ((blk & 127) << 1) + ch;
    int slot = t * 40;                     // ushort offset, 80B stride
    float h00 = h0[2*c], h01 = h0[2*c+1];
    float h10 = h1[2*c], h11 = h1[2*c+1];
    float w0 = w[c], wlast = w[14 * D_ + c];

    const ushort* src = xt + ((size_t)(b * D_ + c)) * L_ + ct * 32;
    float cc[32], y[32];
#pragma unroll
    for (int m = 0; m < 4; ++m) {
        u16x8 v = *(const u16x8*)(src + m * 8);
#pragma unroll
        for (int i = 0; i < 8; ++i) cc[m*8+i] = __uint_as_float(((uint)v[i]) << 16);
    }
#pragma unroll
    for (int i = 0; i < 32; ++i) y[i] = w0 * cc[i];

    LEVEL_SMALL(1, 0);
    LEVEL_SMALL(2, 1);
    LEVEL_SMALL(4, 2);
    LEVEL_SMALL(8, 3);
    LEVEL_SMALL(16, 4);

#pragma unroll 1
    for (int j = 5; j < J_; ++j) {
        int dT = 1 << (j - 5);
        float wj = w[(j + 1) * D_ + c];
#pragma unroll
        for (int m = 0; m < 4; ++m) {
            uint4 pk;
            pk.x = packbf(cc[8*m],   cc[8*m+1]); pk.y = packbf(cc[8*m+2], cc[8*m+3]);
            pk.z = packbf(cc[8*m+4], cc[8*m+5]); pk.w = packbf(cc[8*m+6], cc[8*m+7]);
            *(uint4*)(ex + slot + 8 * m) = pk;
        }
        __syncthreads();
        bool has = (ct >= dT);
        int pbase = slot - dT * 40;
#pragma unroll
        for (int h = 0; h < 2; ++h) {
            float pv[16];
            if (has) {
                uint4 a  = *(const uint4*)(ex + pbase + 16 * h);
                uint4 bq = *(const uint4*)(ex + pbase + 16 * h + 8);
                uint uu[8] = {a.x, a.y, a.z, a.w, bq.x, bq.y, bq.z, bq.w};
#pragma unroll
                for (int q = 0; q < 8; ++q) {
                    pv[2*q]   = __uint_as_float(uu[q] << 16);
                    pv[2*q+1] = __uint_as_float(uu[q] & 0xFFFF0000u);
                }
            } else {
#pragma unroll
                for (int q = 0; q < 16; ++q) pv[q] = 0.f;
            }
#pragma unroll
            for (int i = 0; i < 16; ++i) {
                int e = 16 * h + i;
                float nv = h00 * pv[i] + h01 * cc[e];
                y[e] += wj * (h10 * pv[i] + h11 * cc[e]);
                cc[e] = nv;
            }
        }
        __syncthreads();
    }
    // ---- epilogue: + wlast*a, gelu(tanh approx), bf16 store (64B/thread) ----
    ushort* dst = ygt + ((size_t)(b * D_ + c)) * L_ + ct * 32;
#pragma unroll
    for (int m = 0; m < 4; ++m) {
        float g[8];
#pragma unroll
        for (int q = 0; q < 8; ++q) {
            float v = y[8*m+q] + wlast * cc[8*m+q];
            float u = 0.7978845608028654f * (v + 0.044715f * v * v * v);
            g[q] = 0.5f * v * (1.f + tanhf(u));
        }
        uint4 pk;
        pk.x = packbf(g[0], g[1]); pk.y = packbf(g[2], g[3]);
        pk.z = packbf(g[4], g[5]); pk.w = packbf(g[6], g[7]);
        *(uint4*)(dst + 8 * m) = pk;
    }
}

// ---------------- K2.5: transpose ygt (B,D,L) bf16 -> yg (B,L,D) bf16 ------------
__global__ void trans_kernel(const ushort* __restrict__ ygt, ushort* __restrict__ yg) {
    __shared__ uint tile[64][33];
    int blk = blockIdx.x;            // b*512 + dt*128 + lt
    int b = blk >> 9;
    int rem = blk & 511;
    int dt = rem >> 7, lt = rem & 127;
    int d0 = dt * 64, l0 = lt * 64;
    int tid = threadIdx.x;
    const uint* src = (const uint*)ygt;
#pragma unroll
    for (int k = 0; k < 8; ++k) {
        int i = tid + k * 256;
        int r = i >> 5, cp = i & 31;
        tile[r][cp] = src[(((size_t)(b * D_ + d0 + r)) * L_ + l0) / 2 + cp];
    }
    __syncthreads();
    const ushort* ts = (const ushort*)tile;   // viewed as [64][66]
#pragma unroll
    for (int k = 0; k < 16; ++k) {
        int i = tid + k * 256;
        int r2 = i >> 6, c2 = i & 63;
        yg[((size_t)(b * L_ + l0 + r2)) * D_ + d0 + c2] = ts[c2 * 66 + r2];
    }
}

// ---------------- K3: bf16 MFMA GEMM + bias + GLU + residual ---------------------
__global__ void __launch_bounds__(256) gemm_kernel(
    const ushort* __restrict__ yg, const ushort* __restrict__ Wt,
    const float* __restrict__ cb, const float* __restrict__ x,
    float* __restrict__ out) {
    __shared__ __align__(16) char smem[32768];
    ushort* As = (ushort*)smem;            // [128 rows][8 granules of 8 bf16]
    ushort* Bs = As + 128 * 64;            // same shape
    int blk = blockIdx.x;            // b*256 + ltile*4 + etile
    int b = blk >> 8;
    int rem = blk & 255;
    int ltile = rem >> 2, et = rem & 3;
    int l0 = ltile * 128, e0 = et * 64;
    int tid = threadIdx.x;
    int wave = tid >> 6, lane = tid & 63;
    int wm = wave >> 1, wn = wave & 1;
    int m0 = wm * 64;

    int srow_in = (lane >> 3);             // 0..7 within volley
    int sg = lane & 7;                     // swizzled granule g'
    int sgg = sg ^ srow_in;                // unswizzled granule g
    f32x4 acc[4][4];
#pragma unroll
    for (int i = 0; i < 4; ++i)
#pragma unroll
        for (int j = 0; j < 4; ++j) acc[i][j] = (f32x4)0.f;

    for (int kc = 0; kc < 4; ++kc) {
        __syncthreads();
#pragma unroll
        for (int v = 0; v < 4; ++v) {
            int r = wave * 32 + v * 8 + srow_in;
            async_copy16(yg + ((size_t)(b * L_ + l0 + r)) * D_ + kc * 64 + sgg * 8,
                         As + r * 64 + sg * 8);
            int e = (r < 64) ? (e0 + r) : (256 + e0 + (r - 64));
            async_copy16(Wt + e * 256 + kc * 64 + sgg * 8,
                         Bs + r * 64 + sg * 8);
        }
        __syncthreads();
#pragma unroll
        for (int kk = 0; kk < 2; ++kk) {
            bf16x8 af[4], bfr[4];
            int g = kk * 4 + (lane >> 4);
            int gp = (g ^ (lane & 7)) * 8;
#pragma unroll
            for (int mt = 0; mt < 4; ++mt)
                af[mt] = *(const bf16x8*)(As + (m0 + mt * 16 + (lane & 15)) * 64 + gp);
#pragma unroll
            for (int nt = 0; nt < 4; ++nt) {
                int n = wn * 32 + (nt & 1) * 16 + (nt >> 1) * 64 + (lane & 15);
                bfr[nt] = *(const bf16x8*)(Bs + n * 64 + gp);
            }
#pragma unroll
            for (int mt = 0; mt < 4; ++mt)
#pragma unroll
                for (int nt = 0; nt < 4; ++nt)
                    acc[mt][nt] = __builtin_amdgcn_mfma_f32_16x16x32_bf16(
                        af[mt], bfr[nt], acc[mt][nt], 0, 0, 0);
        }
    }
    __syncthreads();
    float* epi = (float*)smem;
    int row_in = (lane >> 4) * 4;
    int col = lane & 15;
#pragma unroll
    for (int mt = 0; mt < 4; ++mt) {
#pragma unroll
        for (int p = 0; p < 2; ++p) {
            f32x4 uacc = acc[mt][p];
            f32x4 vacc = acc[mt][p + 2];
            int ee = wn * 32 + p * 16 + col;
            float bu = cb[e0 + ee], bv = cb[256 + e0 + ee];
#pragma unroll
            for (int r = 0; r < 4; ++r) {
                int ll = m0 + mt * 16 + row_in + r;
                float u = uacc[r] + bu;
                float v = vacc[r] + bv;
                float g = u / (1.f + __expf(-v));
                epi[ll * 64 + (ee ^ ((ll & 4) ? 16 : 0))] = g;
            }
        }
    }
    __syncthreads();
#pragma unroll
    for (int k = 0; k < 8; ++k) {
        int i = tid + k * 256;
        int ll = i >> 4, e4 = i & 15;
        int exo = (e4 * 4) ^ ((ll & 4) ? 16 : 0);
        float4 gv = *(const float4*)(epi + ll * 64 + exo);
        size_t gidx = ((size_t)(b * L_ + l0 + ll)) * D_ + e0 + e4 * 4;
        float4 xv = *(const float4*)(x + gidx);
        float4 ov;
        ov.x = gv.x + xv.x; ov.y = gv.y + xv.y;
        ov.z = gv.z + xv.z; ov.w = gv.w + xv.w;
        *(float4*)(out + gidx) = ov;
    }
}

extern "C" void kernel_launch(void* const* d_in, const int* in_sizes, int n_in,
                              void* d_out, int out_size, void* d_ws, size_t ws_size,
                              hipStream_t stream) {
    const float* x  = (const float*)d_in[0];
    const float* rs = (const float*)d_in[1];
    const float* h0 = (const float*)d_in[2];
    const float* h1 = (const float*)d_in[3];
    const float* w  = (const float*)d_in[4];
    const float* cw = (const float*)d_in[5];
    const float* cb = (const float*)d_in[6];
    float* out = (float*)d_out;
    char* ws = (char*)d_ws;

    ushort* xtb = (ushort*)ws;                       // 16,777,216 B (bf16)
    ushort* ygt = (ushort*)(ws + 16777216);          // 16,777,216 B (bf16)
    ushort* Wt  = (ushort*)(ws + 33554432);          //    262,144 B (bf16)
    ushort* yg  = (ushort*)ws;                       // alias xtb (dead after cascade)

    rms_wt_kernel<<<1056, 256, 0, stream>>>(x, rs, xtb, cw, Wt);
    cascade_kernel<<<512, 512, 0, stream>>>(xtb, h0, h1, w, ygt);
    trans_kernel<<<2048, 256, 0, stream>>>(ygt, yg);
    gemm_kernel<<<1024, 256, 0, stream>>>(yg, Wt, cb, x, out);
}

// Round 9
// 160.486 us; speedup vs baseline: 1.3006x; 1.2964x over previous
//
#include <hip/hip_runtime.h>
#include <hip/hip_bf16.h>

#define B_ 4
#define L_ 8192
#define D_ 256
#define J_ 13

typedef __attribute__((ext_vector_type(4))) float f32x4;
typedef __attribute__((ext_vector_type(8))) short bf16x8;
typedef __attribute__((ext_vector_type(8))) unsigned short u16x8;

__device__ __forceinline__ void async_copy16(const void* g, void* l) {
    __builtin_amdgcn_global_load_lds(
        (const __attribute__((address_space(1))) void*)g,
        (__attribute__((address_space(3))) void*)l, 16, 0, 0);
}

// pack two f32 -> bf16 pair (round-half-up; inputs finite)
__device__ __forceinline__ unsigned int packbf(float a, float b) {
    unsigned int ua = __float_as_uint(a) + 0x8000u;
    unsigned int ub = __float_as_uint(b) + 0x8000u;
    return (ua >> 16) | (ub & 0xFFFF0000u);
}
__device__ __forceinline__ unsigned short packbf1(float a) {
    return (unsigned short)((__float_as_uint(a) + 0x8000u) >> 16);
}

// ---------------- K1: fused wt-transpose (blocks 0..31) + RMSNorm/transpose ------
__global__ void rms_wt_kernel(const float* __restrict__ x, const float* __restrict__ scale,
                              ushort* __restrict__ xtb,
                              const float* __restrict__ W, ushort* __restrict__ Wt) {
    __shared__ __align__(16) float sm[32 * 257 + 32];
    int blk = blockIdx.x;
    int tid = threadIdx.x;
    if (blk < 32) {
        float (*tile)[65] = (float(*)[65])sm;
        int dt = blk >> 3, et = blk & 7;
        int d0 = dt * 64, e0 = et * 64;
#pragma unroll
        for (int k = 0; k < 16; ++k) {
            int i = tid + k * 256;
            int r = i >> 6, c = i & 63;
            tile[r][c] = W[(d0 + r) * 512 + e0 + c];
        }
        __syncthreads();
#pragma unroll
        for (int k = 0; k < 16; ++k) {
            int i = tid + k * 256;
            int r = i >> 6, c = i & 63;
            Wt[(e0 + r) * 256 + d0 + c] = packbf1(tile[c][r]);
        }
        return;
    }
    blk -= 32;                        // b*256 + ltile
    float (*tile)[257] = (float(*)[257])sm;
    float* invl = sm + 32 * 257;
    int b  = blk >> 8;
    int l0 = (blk & 255) << 5;
    const float* src = x + ((size_t)(b * L_ + l0)) * D_;
#pragma unroll
    for (int k = 0; k < 32; ++k) tile[k][tid] = src[k * D_ + tid];
    __syncthreads();
    int wave = tid >> 6, lane = tid & 63;
#pragma unroll
    for (int rr = 0; rr < 8; ++rr) {
        int r = wave * 8 + rr;
        float s = 0.f;
#pragma unroll
        for (int q = 0; q < 4; ++q) { float v = tile[r][lane + 64 * q]; s += v * v; }
#pragma unroll
        for (int off = 32; off; off >>= 1) s += __shfl_xor(s, off);
        if (lane == 0) invl[r] = rsqrtf(s * (1.0f / 256.0f) + 1e-6f);
    }
    __syncthreads();
    uint* dst32 = (uint*)xtb;
#pragma unroll
    for (int k = 0; k < 16; ++k) {
        int i = tid + k * 256;         // 4096 (d, l-pair) slots
        int d = i >> 4, lp = (i & 15) * 2;
        float v0 = tile[lp][d]     * invl[lp]     * scale[d];
        float v1 = tile[lp + 1][d] * invl[lp + 1] * scale[d];
        dst32[(((size_t)(b * D_ + d)) * L_ + l0 + lp) >> 1] = packbf(v0, v1);
    }
}

// ---------------- K2: 13-level dilated depthwise cascade + gelu ------------------
// 2 channels/block, 512 threads (256/channel), 32 f32 elems/thread in registers.
// R8 lesson: the VGPR budget tracks LDS-limited occupancy, not launch-bounds
// hints (R2: 64KB LDS -> 128 VGPR; R7/R8: 40KB -> 64 VGPR + spill). Pad LDS to
// 56KB (>160/3) -> <=2 blocks/CU -> 4 waves/EU -> 128-VGPR budget. Grid is
// 2 blocks/CU anyway, so the padding costs no real occupancy.
#define LEVEL_SMALL(d, jj)                                                       \
    do {                                                                         \
        uint4 pk;                                                                \
        pk.x = packbf(cc[16], cc[17]); pk.y = packbf(cc[18], cc[19]);            \
        pk.z = packbf(cc[20], cc[21]); pk.w = packbf(cc[22], cc[23]);            \
        *(uint4*)(ex + slot + 16) = pk;                                          \
        pk.x = packbf(cc[24], cc[25]); pk.y = packbf(cc[26], cc[27]);            \
        pk.z = packbf(cc[28], cc[29]); pk.w = packbf(cc[30], cc[31]);            \
        *(uint4*)(ex + slot + 24) = pk;                                          \
        __syncthreads();                                                         \
        float pt[16];                                                            \
        if (ct > 0) {                                                            \
            uint4 a  = *(const uint4*)(ex + slot - 40 + 16);                     \
            uint4 bq = *(const uint4*)(ex + slot - 40 + 24);                     \
            uint uu[8] = {a.x, a.y, a.z, a.w, bq.x, bq.y, bq.z, bq.w};           \
            _Pragma("unroll") for (int q = 0; q < 8; ++q) {                      \
                pt[2*q]   = __uint_as_float(uu[q] << 16);                        \
                pt[2*q+1] = __uint_as_float(uu[q] & 0xFFFF0000u); }              \
        } else { _Pragma("unroll") for (int q = 0; q < 16; ++q) pt[q] = 0.f; }   \
        __syncthreads();                                                         \
        float wj = w[((jj) + 1) * D_ + c];                                       \
        _Pragma("unroll")                                                        \
        for (int i = 31; i >= 0; --i) {                                          \
            float pv = (i >= (d)) ? cc[i - (d)] : pt[16 + i - (d)];              \
            float nv = h00 * pv + h01 * cc[i];                                   \
            y[i] += wj * (h10 * pv + h11 * cc[i]);                               \
            cc[i] = nv;                                                          \
        }                                                                        \
    } while (0)

__global__ void __launch_bounds__(512) cascade_kernel(
    const ushort* __restrict__ xt, const float* __restrict__ h0,
    const float* __restrict__ h1, const float* __restrict__ w,
    ushort* __restrict__ ygt) {
    __shared__ __align__(16) ushort ex[512 * 56];   // 56 KB (40 used; pad caps occupancy)
    int blk = blockIdx.x;                  // b*128 + cpair
    int b = blk >> 7;
    int t = threadIdx.x;
    int ch = t >> 8;
    int ct = t & 255;
    int c = ((blk & 127) << 1) + ch;
    int slot = t * 40;                     // ushort offset, 80B stride
    float h00 = h0[2*c], h01 = h0[2*c+1];
    float h10 = h1[2*c], h11 = h1[2*c+1];
    float w0 = w[c], wlast = w[14 * D_ + c];

    const ushort* src = xt + ((size_t)(b * D_ + c)) * L_ + ct * 32;
    float cc[32], y[32];
#pragma unroll
    for (int m = 0; m < 4; ++m) {
        u16x8 v = *(const u16x8*)(src + m * 8);
#pragma unroll
        for (int i = 0; i < 8; ++i) cc[m*8+i] = __uint_as_float(((uint)v[i]) << 16);
    }
#pragma unroll
    for (int i = 0; i < 32; ++i) y[i] = w0 * cc[i];

    LEVEL_SMALL(1, 0);
    LEVEL_SMALL(2, 1);
    LEVEL_SMALL(4, 2);
    LEVEL_SMALL(8, 3);
    LEVEL_SMALL(16, 4);

#pragma unroll 1
    for (int j = 5; j < J_; ++j) {
        int dT = 1 << (j - 5);
        float wj = w[(j + 1) * D_ + c];
#pragma unroll
        for (int m = 0; m < 4; ++m) {
            uint4 pk;
            pk.x = packbf(cc[8*m],   cc[8*m+1]); pk.y = packbf(cc[8*m+2], cc[8*m+3]);
            pk.z = packbf(cc[8*m+4], cc[8*m+5]); pk.w = packbf(cc[8*m+6], cc[8*m+7]);
            *(uint4*)(ex + slot + 8 * m) = pk;
        }
        __syncthreads();
        bool has = (ct >= dT);
        int pbase = slot - dT * 40;
#pragma unroll
        for (int h = 0; h < 2; ++h) {
            float pv[16];
            if (has) {
                uint4 a  = *(const uint4*)(ex + pbase + 16 * h);
                uint4 bq = *(const uint4*)(ex + pbase + 16 * h + 8);
                uint uu[8] = {a.x, a.y, a.z, a.w, bq.x, bq.y, bq.z, bq.w};
#pragma unroll
                for (int q = 0; q < 8; ++q) {
                    pv[2*q]   = __uint_as_float(uu[q] << 16);
                    pv[2*q+1] = __uint_as_float(uu[q] & 0xFFFF0000u);
                }
            } else {
#pragma unroll
                for (int q = 0; q < 16; ++q) pv[q] = 0.f;
            }
#pragma unroll
            for (int i = 0; i < 16; ++i) {
                int e = 16 * h + i;
                float nv = h00 * pv[i] + h01 * cc[e];
                y[e] += wj * (h10 * pv[i] + h11 * cc[e]);
                cc[e] = nv;
            }
        }
        __syncthreads();
    }
    // ---- epilogue: + wlast*a, gelu(tanh approx), bf16 store (64B/thread) ----
    ushort* dst = ygt + ((size_t)(b * D_ + c)) * L_ + ct * 32;
#pragma unroll
    for (int m = 0; m < 4; ++m) {
        float g[8];
#pragma unroll
        for (int q = 0; q < 8; ++q) {
            float v = y[8*m+q] + wlast * cc[8*m+q];
            float u = 0.7978845608028654f * (v + 0.044715f * v * v * v);
            g[q] = 0.5f * v * (1.f + tanhf(u));
        }
        uint4 pk;
        pk.x = packbf(g[0], g[1]); pk.y = packbf(g[2], g[3]);
        pk.z = packbf(g[4], g[5]); pk.w = packbf(g[6], g[7]);
        *(uint4*)(dst + 8 * m) = pk;
    }
}

// ---------------- K2.5: transpose ygt (B,D,L) bf16 -> yg (B,L,D) bf16 ------------
__global__ void trans_kernel(const ushort* __restrict__ ygt, ushort* __restrict__ yg) {
    __shared__ uint tile[64][33];
    int blk = blockIdx.x;            // b*512 + dt*128 + lt
    int b = blk >> 9;
    int rem = blk & 511;
    int dt = rem >> 7, lt = rem & 127;
    int d0 = dt * 64, l0 = lt * 64;
    int tid = threadIdx.x;
    const uint* src = (const uint*)ygt;
#pragma unroll
    for (int k = 0; k < 8; ++k) {
        int i = tid + k * 256;
        int r = i >> 5, cp = i & 31;
        tile[r][cp] = src[(((size_t)(b * D_ + d0 + r)) * L_ + l0) / 2 + cp];
    }
    __syncthreads();
    const ushort* ts = (const ushort*)tile;   // viewed as [64][66]
#pragma unroll
    for (int k = 0; k < 16; ++k) {
        int i = tid + k * 256;
        int r2 = i >> 6, c2 = i & 63;
        yg[((size_t)(b * L_ + l0 + r2)) * D_ + d0 + c2] = ts[c2 * 66 + r2];
    }
}

// ---------------- K3: bf16 MFMA GEMM + bias + GLU + residual ---------------------
__global__ void __launch_bounds__(256) gemm_kernel(
    const ushort* __restrict__ yg, const ushort* __restrict__ Wt,
    const float* __restrict__ cb, const float* __restrict__ x,
    float* __restrict__ out) {
    __shared__ __align__(16) char smem[32768];
    ushort* As = (ushort*)smem;            // [128 rows][8 granules of 8 bf16]
    ushort* Bs = As + 128 * 64;            // same shape
    int blk = blockIdx.x;            // b*256 + ltile*4 + etile
    int b = blk >> 8;
    int rem = blk & 255;
    int ltile = rem >> 2, et = rem & 3;
    int l0 = ltile * 128, e0 = et * 64;
    int tid = threadIdx.x;
    int wave = tid >> 6, lane = tid & 63;
    int wm = wave >> 1, wn = wave & 1;
    int m0 = wm * 64;

    int srow_in = (lane >> 3);             // 0..7 within volley
    int sg = lane & 7;                     // swizzled granule g'
    int sgg = sg ^ srow_in;                // unswizzled granule g
    f32x4 acc[4][4];
#pragma unroll
    for (int i = 0; i < 4; ++i)
#pragma unroll
        for (int j = 0; j < 4; ++j) acc[i][j] = (f32x4)0.f;

    for (int kc = 0; kc < 4; ++kc) {
        __syncthreads();
#pragma unroll
        for (int v = 0; v < 4; ++v) {
            int r = wave * 32 + v * 8 + srow_in;
            async_copy16(yg + ((size_t)(b * L_ + l0 + r)) * D_ + kc * 64 + sgg * 8,
                         As + r * 64 + sg * 8);
            int e = (r < 64) ? (e0 + r) : (256 + e0 + (r - 64));
            async_copy16(Wt + e * 256 + kc * 64 + sgg * 8,
                         Bs + r * 64 + sg * 8);
        }
        __syncthreads();
#pragma unroll
        for (int kk = 0; kk < 2; ++kk) {
            bf16x8 af[4], bfr[4];
            int g = kk * 4 + (lane >> 4);
            int gp = (g ^ (lane & 7)) * 8;
#pragma unroll
            for (int mt = 0; mt < 4; ++mt)
                af[mt] = *(const bf16x8*)(As + (m0 + mt * 16 + (lane & 15)) * 64 + gp);
#pragma unroll
            for (int nt = 0; nt < 4; ++nt) {
                int n = wn * 32 + (nt & 1) * 16 + (nt >> 1) * 64 + (lane & 15);
                bfr[nt] = *(const bf16x8*)(Bs + n * 64 + gp);
            }
#pragma unroll
            for (int mt = 0; mt < 4; ++mt)
#pragma unroll
                for (int nt = 0; nt < 4; ++nt)
                    acc[mt][nt] = __builtin_amdgcn_mfma_f32_16x16x32_bf16(
                        af[mt], bfr[nt], acc[mt][nt], 0, 0, 0);
        }
    }
    __syncthreads();
    float* epi = (float*)smem;
    int row_in = (lane >> 4) * 4;
    int col = lane & 15;
#pragma unroll
    for (int mt = 0; mt < 4; ++mt) {
#pragma unroll
        for (int p = 0; p < 2; ++p) {
            f32x4 uacc = acc[mt][p];
            f32x4 vacc = acc[mt][p + 2];
            int ee = wn * 32 + p * 16 + col;
            float bu = cb[e0 + ee], bv = cb[256 + e0 + ee];
#pragma unroll
            for (int r = 0; r < 4; ++r) {
                int ll = m0 + mt * 16 + row_in + r;
                float u = uacc[r] + bu;
                float v = vacc[r] + bv;
                float g = u / (1.f + __expf(-v));
                epi[ll * 64 + (ee ^ ((ll & 4) ? 16 : 0))] = g;
            }
        }
    }
    __syncthreads();
#pragma unroll
    for (int k = 0; k < 8; ++k) {
        int i = tid + k * 256;
        int ll = i >> 4, e4 = i & 15;
        int exo = (e4 * 4) ^ ((ll & 4) ? 16 : 0);
        float4 gv = *(const float4*)(epi + ll * 64 + exo);
        size_t gidx = ((size_t)(b * L_ + l0 + ll)) * D_ + e0 + e4 * 4;
        float4 xv = *(const float4*)(x + gidx);
        float4 ov;
        ov.x = gv.x + xv.x; ov.y = gv.y + xv.y;
        ov.z = gv.z + xv.z; ov.w = gv.w + xv.w;
        *(float4*)(out + gidx) = ov;
    }
}

extern "C" void kernel_launch(void* const* d_in, const int* in_sizes, int n_in,
                              void* d_out, int out_size, void* d_ws, size_t ws_size,
                              hipStream_t stream) {
    const float* x  = (const float*)d_in[0];
    const float* rs = (const float*)d_in[1];
    const float* h0 = (const float*)d_in[2];
    const float* h1 = (const float*)d_in[3];
    const float* w  = (const float*)d_in[4];
    const float* cw = (const float*)d_in[5];
    const float* cb = (const float*)d_in[6];
    float* out = (float*)d_out;
    char* ws = (char*)d_ws;

    ushort* xtb = (ushort*)ws;                       // 16,777,216 B (bf16)
    ushort* ygt = (ushort*)(ws + 16777216);          // 16,777,216 B (bf16)
    ushort* Wt  = (ushort*)(ws + 33554432);          //    262,144 B (bf16)
    ushort* yg  = (ushort*)ws;                       // alias xtb (dead after cascade)

    rms_wt_kernel<<<1056, 256, 0, stream>>>(x, rs, xtb, cw, Wt);
    cascade_kernel<<<512, 512, 0, stream>>>(xtb, h0, h1, w, ygt);
    trans_kernel<<<2048, 256, 0, stream>>>(ygt, yg);
    gemm_kernel<<<1024, 256, 0, stream>>>(yg, Wt, cb, x, out);
}

// Round 10
// 160.093 us; speedup vs baseline: 1.3038x; 1.0025x over previous
//
#include <hip/hip_runtime.h>
#include <hip/hip_bf16.h>

#define B_ 4
#define L_ 8192
#define D_ 256
#define J_ 13

typedef __attribute__((ext_vector_type(4))) float f32x4;
typedef __attribute__((ext_vector_type(8))) short bf16x8;
typedef __attribute__((ext_vector_type(8))) unsigned short u16x8;

__device__ __forceinline__ void async_copy16(const void* g, void* l) {
    __builtin_amdgcn_global_load_lds(
        (const __attribute__((address_space(1))) void*)g,
        (__attribute__((address_space(3))) void*)l, 16, 0, 0);
}

// pack two f32 -> bf16 pair (round-half-up; inputs finite)
__device__ __forceinline__ unsigned int packbf(float a, float b) {
    unsigned int ua = __float_as_uint(a) + 0x8000u;
    unsigned int ub = __float_as_uint(b) + 0x8000u;
    return (ua >> 16) | (ub & 0xFFFF0000u);
}
__device__ __forceinline__ unsigned short packbf1(float a) {
    return (unsigned short)((__float_as_uint(a) + 0x8000u) >> 16);
}

// ---------------- K1: fused wt-transpose (blocks 0..31) + RMSNorm/transpose ------
// rms global loads are float4 (16B/lane); LDS tile row stride 260 (mult of 4)
// keeps b128 LDS writes 16B-aligned and bank-minimal.
__global__ void rms_wt_kernel(const float* __restrict__ x, const float* __restrict__ scale,
                              ushort* __restrict__ xtb,
                              const float* __restrict__ W, ushort* __restrict__ Wt) {
    __shared__ __align__(16) float sm[32 * 260 + 32];
    int blk = blockIdx.x;
    int tid = threadIdx.x;
    if (blk < 32) {
        float (*tile)[65] = (float(*)[65])sm;
        int dt = blk >> 3, et = blk & 7;
        int d0 = dt * 64, e0 = et * 64;
#pragma unroll
        for (int k = 0; k < 16; ++k) {
            int i = tid + k * 256;
            int r = i >> 6, c = i & 63;
            tile[r][c] = W[(d0 + r) * 512 + e0 + c];
        }
        __syncthreads();
#pragma unroll
        for (int k = 0; k < 16; ++k) {
            int i = tid + k * 256;
            int r = i >> 6, c = i & 63;
            Wt[(e0 + r) * 256 + d0 + c] = packbf1(tile[c][r]);
        }
        return;
    }
    blk -= 32;                        // b*256 + ltile
    float (*tile)[260] = (float(*)[260])sm;
    float* invl = sm + 32 * 260;
    int b  = blk >> 8;
    int l0 = (blk & 255) << 5;
    const float* src = x + ((size_t)(b * L_ + l0)) * D_;
#pragma unroll
    for (int k = 0; k < 8; ++k) {
        int i = tid + k * 256;         // 2048 float4 slots
        int r = i >> 6, c4 = i & 63;
        *(float4*)&tile[r][c4 * 4] = *(const float4*)(src + r * D_ + c4 * 4);
    }
    __syncthreads();
    int wave = tid >> 6, lane = tid & 63;
#pragma unroll
    for (int rr = 0; rr < 8; ++rr) {
        int r = wave * 8 + rr;
        float s = 0.f;
#pragma unroll
        for (int q = 0; q < 4; ++q) { float v = tile[r][lane + 64 * q]; s += v * v; }
#pragma unroll
        for (int off = 32; off; off >>= 1) s += __shfl_xor(s, off);
        if (lane == 0) invl[r] = rsqrtf(s * (1.0f / 256.0f) + 1e-6f);
    }
    __syncthreads();
    uint* dst32 = (uint*)xtb;
#pragma unroll
    for (int k = 0; k < 16; ++k) {
        int i = tid + k * 256;         // 4096 (d, l-pair) slots
        int d = i >> 4, lp = (i & 15) * 2;
        float v0 = tile[lp][d]     * invl[lp]     * scale[d];
        float v1 = tile[lp + 1][d] * invl[lp + 1] * scale[d];
        dst32[(((size_t)(b * D_ + d)) * L_ + l0 + lp) >> 1] = packbf(v0, v1);
    }
}

// ---------------- K2: 13-level dilated depthwise cascade + gelu ------------------
// 2 channels/block, 512 threads, 32 f32 elems/thread in registers.
// R8/R9 lesson: VGPR budget tracks LDS-limited occupancy (>=54KB LDS -> 2
// blocks/CU -> 128-VGPR budget, no spill). R10: DOUBLE-BUFFERED exchange
// (level j uses buffer j&1) -> ONE barrier per level (13 vs 26). Level j+2's
// buffer reuse is ordered behind level j's reads by level j+1's barrier.
// 80KB LDS keeps exactly 2 blocks/CU.
#define LEVEL_SMALL(d, jj, buf)                                                  \
    do {                                                                         \
        uint4 pk;                                                                \
        pk.x = packbf(cc[16], cc[17]); pk.y = packbf(cc[18], cc[19]);            \
        pk.z = packbf(cc[20], cc[21]); pk.w = packbf(cc[22], cc[23]);            \
        *(uint4*)((buf) + slot + 16) = pk;                                       \
        pk.x = packbf(cc[24], cc[25]); pk.y = packbf(cc[26], cc[27]);            \
        pk.z = packbf(cc[28], cc[29]); pk.w = packbf(cc[30], cc[31]);            \
        *(uint4*)((buf) + slot + 24) = pk;                                       \
        __syncthreads();                                                         \
        float pt[16];                                                            \
        if (ct > 0) {                                                            \
            uint4 a  = *(const uint4*)((buf) + slot - 40 + 16);                  \
            uint4 bq = *(const uint4*)((buf) + slot - 40 + 24);                  \
            uint uu[8] = {a.x, a.y, a.z, a.w, bq.x, bq.y, bq.z, bq.w};           \
            _Pragma("unroll") for (int q = 0; q < 8; ++q) {                      \
                pt[2*q]   = __uint_as_float(uu[q] << 16);                        \
                pt[2*q+1] = __uint_as_float(uu[q] & 0xFFFF0000u); }              \
        } else { _Pragma("unroll") for (int q = 0; q < 16; ++q) pt[q] = 0.f; }   \
        float wj = w[((jj) + 1) * D_ + c];                                       \
        _Pragma("unroll")                                                        \
        for (int i = 31; i >= 0; --i) {                                          \
            float pv = (i >= (d)) ? cc[i - (d)] : pt[16 + i - (d)];              \
            float nv = h00 * pv + h01 * cc[i];                                   \
            y[i] += wj * (h10 * pv + h11 * cc[i]);                               \
            cc[i] = nv;                                                          \
        }                                                                        \
    } while (0)

__global__ void __launch_bounds__(512) cascade_kernel(
    const ushort* __restrict__ xt, const float* __restrict__ h0,
    const float* __restrict__ h1, const float* __restrict__ w,
    ushort* __restrict__ ygt) {
    __shared__ __align__(16) ushort ex[2 * 512 * 40];   // 80 KB double-buffered
    ushort* bufA = ex;
    ushort* bufB = ex + 512 * 40;
    int blk = blockIdx.x;                  // b*128 + cpair
    int b = blk >> 7;
    int t = threadIdx.x;
    int ch = t >> 8;
    int ct = t & 255;
    int c = ((blk & 127) << 1) + ch;
    int slot = t * 40;                     // ushort offset, 80B stride
    float h00 = h0[2*c], h01 = h0[2*c+1];
    float h10 = h1[2*c], h11 = h1[2*c+1];
    float w0 = w[c], wlast = w[14 * D_ + c];

    const ushort* src = xt + ((size_t)(b * D_ + c)) * L_ + ct * 32;
    float cc[32], y[32];
#pragma unroll
    for (int m = 0; m < 4; ++m) {
        u16x8 v = *(const u16x8*)(src + m * 8);
#pragma unroll
        for (int i = 0; i < 8; ++i) cc[m*8+i] = __uint_as_float(((uint)v[i]) << 16);
    }
#pragma unroll
    for (int i = 0; i < 32; ++i) y[i] = w0 * cc[i];

    LEVEL_SMALL(1, 0, bufA);
    LEVEL_SMALL(2, 1, bufB);
    LEVEL_SMALL(4, 2, bufA);
    LEVEL_SMALL(8, 3, bufB);
    LEVEL_SMALL(16, 4, bufA);

#pragma unroll 1
    for (int j = 5; j < J_; ++j) {
        int dT = 1 << (j - 5);
        float wj = w[(j + 1) * D_ + c];
        ushort* buf = (j & 1) ? bufB : bufA;
#pragma unroll
        for (int m = 0; m < 4; ++m) {
            uint4 pk;
            pk.x = packbf(cc[8*m],   cc[8*m+1]); pk.y = packbf(cc[8*m+2], cc[8*m+3]);
            pk.z = packbf(cc[8*m+4], cc[8*m+5]); pk.w = packbf(cc[8*m+6], cc[8*m+7]);
            *(uint4*)(buf + slot + 8 * m) = pk;
        }
        __syncthreads();
        bool has = (ct >= dT);
        int pbase = slot - dT * 40;
#pragma unroll
        for (int h = 0; h < 2; ++h) {
            float pv[16];
            if (has) {
                uint4 a  = *(const uint4*)(buf + pbase + 16 * h);
                uint4 bq = *(const uint4*)(buf + pbase + 16 * h + 8);
                uint uu[8] = {a.x, a.y, a.z, a.w, bq.x, bq.y, bq.z, bq.w};
#pragma unroll
                for (int q = 0; q < 8; ++q) {
                    pv[2*q]   = __uint_as_float(uu[q] << 16);
                    pv[2*q+1] = __uint_as_float(uu[q] & 0xFFFF0000u);
                }
            } else {
#pragma unroll
                for (int q = 0; q < 16; ++q) pv[q] = 0.f;
            }
#pragma unroll
            for (int i = 0; i < 16; ++i) {
                int e = 16 * h + i;
                float nv = h00 * pv[i] + h01 * cc[e];
                y[e] += wj * (h10 * pv[i] + h11 * cc[e]);
                cc[e] = nv;
            }
        }
    }
    // ---- epilogue: + wlast*a, gelu(tanh approx), bf16 store (64B/thread) ----
    ushort* dst = ygt + ((size_t)(b * D_ + c)) * L_ + ct * 32;
#pragma unroll
    for (int m = 0; m < 4; ++m) {
        float g[8];
#pragma unroll
        for (int q = 0; q < 8; ++q) {
            float v = y[8*m+q] + wlast * cc[8*m+q];
            float u = 0.7978845608028654f * (v + 0.044715f * v * v * v);
            g[q] = 0.5f * v * (1.f + tanhf(u));
        }
        uint4 pk;
        pk.x = packbf(g[0], g[1]); pk.y = packbf(g[2], g[3]);
        pk.z = packbf(g[4], g[5]); pk.w = packbf(g[6], g[7]);
        *(uint4*)(dst + 8 * m) = pk;
    }
}

// ---------------- K2.5: transpose ygt (B,D,L) bf16 -> yg (B,L,D) bf16 ------------
__global__ void trans_kernel(const ushort* __restrict__ ygt, ushort* __restrict__ yg) {
    __shared__ uint tile[64][33];
    int blk = blockIdx.x;            // b*512 + dt*128 + lt
    int b = blk >> 9;
    int rem = blk & 511;
    int dt = rem >> 7, lt = rem & 127;
    int d0 = dt * 64, l0 = lt * 64;
    int tid = threadIdx.x;
    const uint* src = (const uint*)ygt;
#pragma unroll
    for (int k = 0; k < 8; ++k) {
        int i = tid + k * 256;
        int r = i >> 5, cp = i & 31;
        tile[r][cp] = src[(((size_t)(b * D_ + d0 + r)) * L_ + l0) / 2 + cp];
    }
    __syncthreads();
    const ushort* ts = (const ushort*)tile;   // viewed as [64][66]
#pragma unroll
    for (int k = 0; k < 16; ++k) {
        int i = tid + k * 256;
        int r2 = i >> 6, c2 = i & 63;
        yg[((size_t)(b * L_ + l0 + r2)) * D_ + d0 + c2] = ts[c2 * 66 + r2];
    }
}

// ---------------- K3: bf16 MFMA GEMM + bias + GLU + residual ---------------------
__global__ void __launch_bounds__(256) gemm_kernel(
    const ushort* __restrict__ yg, const ushort* __restrict__ Wt,
    const float* __restrict__ cb, const float* __restrict__ x,
    float* __restrict__ out) {
    __shared__ __align__(16) char smem[32768];
    ushort* As = (ushort*)smem;            // [128 rows][8 granules of 8 bf16]
    ushort* Bs = As + 128 * 64;            // same shape
    int blk = blockIdx.x;            // b*256 + ltile*4 + etile
    int b = blk >> 8;
    int rem = blk & 255;
    int ltile = rem >> 2, et = rem & 3;
    int l0 = ltile * 128, e0 = et * 64;
    int tid = threadIdx.x;
    int wave = tid >> 6, lane = tid & 63;
    int wm = wave >> 1, wn = wave & 1;
    int m0 = wm * 64;

    int srow_in = (lane >> 3);             // 0..7 within volley
    int sg = lane & 7;                     // swizzled granule g'
    int sgg = sg ^ srow_in;                // unswizzled granule g
    f32x4 acc[4][4];
#pragma unroll
    for (int i = 0; i < 4; ++i)
#pragma unroll
        for (int j = 0; j < 4; ++j) acc[i][j] = (f32x4)0.f;

    for (int kc = 0; kc < 4; ++kc) {
        __syncthreads();
#pragma unroll
        for (int v = 0; v < 4; ++v) {
            int r = wave * 32 + v * 8 + srow_in;
            async_copy16(yg + ((size_t)(b * L_ + l0 + r)) * D_ + kc * 64 + sgg * 8,
                         As + r * 64 + sg * 8);
            int e = (r < 64) ? (e0 + r) : (256 + e0 + (r - 64));
            async_copy16(Wt + e * 256 + kc * 64 + sgg * 8,
                         Bs + r * 64 + sg * 8);
        }
        __syncthreads();
#pragma unroll
        for (int kk = 0; kk < 2; ++kk) {
            bf16x8 af[4], bfr[4];
            int g = kk * 4 + (lane >> 4);
            int gp = (g ^ (lane & 7)) * 8;
#pragma unroll
            for (int mt = 0; mt < 4; ++mt)
                af[mt] = *(const bf16x8*)(As + (m0 + mt * 16 + (lane & 15)) * 64 + gp);
#pragma unroll
            for (int nt = 0; nt < 4; ++nt) {
                int n = wn * 32 + (nt & 1) * 16 + (nt >> 1) * 64 + (lane & 15);
                bfr[nt] = *(const bf16x8*)(Bs + n * 64 + gp);
            }
#pragma unroll
            for (int mt = 0; mt < 4; ++mt)
#pragma unroll
                for (int nt = 0; nt < 4; ++nt)
                    acc[mt][nt] = __builtin_amdgcn_mfma_f32_16x16x32_bf16(
                        af[mt], bfr[nt], acc[mt][nt], 0, 0, 0);
        }
    }
    __syncthreads();
    float* epi = (float*)smem;
    int row_in = (lane >> 4) * 4;
    int col = lane & 15;
#pragma unroll
    for (int mt = 0; mt < 4; ++mt) {
#pragma unroll
        for (int p = 0; p < 2; ++p) {
            f32x4 uacc = acc[mt][p];
            f32x4 vacc = acc[mt][p + 2];
            int ee = wn * 32 + p * 16 + col;
            float bu = cb[e0 + ee], bv = cb[256 + e0 + ee];
#pragma unroll
            for (int r = 0; r < 4; ++r) {
                int ll = m0 + mt * 16 + row_in + r;
                float u = uacc[r] + bu;
                float v = vacc[r] + bv;
                float g = u / (1.f + __expf(-v));
                epi[ll * 64 + (ee ^ ((ll & 4) ? 16 : 0))] = g;
            }
        }
    }
    __syncthreads();
#pragma unroll
    for (int k = 0; k < 8; ++k) {
        int i = tid + k * 256;
        int ll = i >> 4, e4 = i & 15;
        int exo = (e4 * 4) ^ ((ll & 4) ? 16 : 0);
        float4 gv = *(const float4*)(epi + ll * 64 + exo);
        size_t gidx = ((size_t)(b * L_ + l0 + ll)) * D_ + e0 + e4 * 4;
        float4 xv = *(const float4*)(x + gidx);
        float4 ov;
        ov.x = gv.x + xv.x; ov.y = gv.y + xv.y;
        ov.z = gv.z + xv.z; ov.w = gv.w + xv.w;
        *(float4*)(out + gidx) = ov;
    }
}

extern "C" void kernel_launch(void* const* d_in, const int* in_sizes, int n_in,
                              void* d_out, int out_size, void* d_ws, size_t ws_size,
                              hipStream_t stream) {
    const float* x  = (const float*)d_in[0];
    const float* rs = (const float*)d_in[1];
    const float* h0 = (const float*)d_in[2];
    const float* h1 = (const float*)d_in[3];
    const float* w  = (const float*)d_in[4];
    const float* cw = (const float*)d_in[5];
    const float* cb = (const float*)d_in[6];
    float* out = (float*)d_out;
    char* ws = (char*)d_ws;

    ushort* xtb = (ushort*)ws;                       // 16,777,216 B (bf16)
    ushort* ygt = (ushort*)(ws + 16777216);          // 16,777,216 B (bf16)
    ushort* Wt  = (ushort*)(ws + 33554432);          //    262,144 B (bf16)
    ushort* yg  = (ushort*)ws;                       // alias xtb (dead after cascade)

    rms_wt_kernel<<<1056, 256, 0, stream>>>(x, rs, xtb, cw, Wt);
    cascade_kernel<<<512, 512, 0, stream>>>(xtb, h0, h1, w, ygt);
    trans_kernel<<<2048, 256, 0, stream>>>(ygt, yg);
    gemm_kernel<<<1024, 256, 0, stream>>>(yg, Wt, cb, x, out);
}